// Round 6
// baseline (331.782 us; speedup 1.0000x reference)
//
#include <hip/hip_runtime.h>
#include <hip/hip_bf16.h>
#include <math.h>

// Problem constants (StructureGuidedAttention: B=4, S=1024, D=1024, H=16, dk=64, G=7)
#define BB 4
#define SS 1024
#define DD 1024
#define NH 16
#define DK 64
#define GD 7

typedef _Float16 half8 __attribute__((ext_vector_type(8)));
typedef _Float16 half4v __attribute__((ext_vector_type(4)));
typedef float floatx4 __attribute__((ext_vector_type(4)));

// async global->LDS 16B DMA. Dest is wave-uniform base + lane*16 (linear);
// swizzling is done by PRE-SWIZZLING the per-lane global source address.
__device__ __forceinline__ void async_cp16(const void* g, void* l) {
  __builtin_amdgcn_global_load_lds(
      (const __attribute__((address_space(1))) void*)g,
      (__attribute__((address_space(3))) void*)l, 16, 0, 0);
}

__device__ inline half8 cvt8(const float4 a, const float4 b) {
  half8 h;
  h[0] = (_Float16)a.x; h[1] = (_Float16)a.y; h[2] = (_Float16)a.z; h[3] = (_Float16)a.w;
  h[4] = (_Float16)b.x; h[5] = (_Float16)b.y; h[6] = (_Float16)b.z; h[7] = (_Float16)b.w;
  return h;
}

// ---------------------------------------------------------------------------
// prep2: merged streaming pass. PRE=true: 7168 blocks, roles interleaved
// 4:2:1 (biasprep : cvtx : packw); PRE=false: 3072 blocks, cvtx + packw only.
// biasprep re-partitioned: 4 keys/thread (28 geom floats live, not 56) so the
// live range fits regalloc's comfort zone — rounds 4/5 showed the compiler
// rematerializes the geom loads inside the 16-head loop when 56 floats are
// live (VGPR pinned at 56, 224 re-issued loads/thread, latency-bound).
// ---------------------------------------------------------------------------
template <bool PRE>
__global__ __launch_bounds__(256) void prep2(const float* __restrict__ x,
                                             _Float16* __restrict__ xh,
                                             const float* __restrict__ Wq,
                                             const float* __restrict__ Wk,
                                             const float* __restrict__ Wv,
                                             const float* __restrict__ Wo,
                                             _Float16* __restrict__ Wt,
                                             const float* __restrict__ geom,
                                             const int* __restrict__ mask,
                                             const float* __restrict__ Wg,
                                             const float* __restrict__ bg,
                                             unsigned char* __restrict__ bias8) {
  __shared__ _Float16 Tl[64 * 72];       // packw transpose tile [n][k], pitch 72
  __shared__ float wgL[GD * NH + NH];    // biasprep weights
  const int t = threadIdx.x;
  int role, idx;
  if (PRE) {
    const int grp = blockIdx.x / 7, rem = blockIdx.x % 7;  // 7168 = 7*1024
    if (rem < 4)      { role = 0; idx = grp * 4 + rem; }       // biasprep 0..4095
    else if (rem < 6) { role = 1; idx = grp * 2 + rem - 4; }   // cvtx 0..2047
    else              { role = 2; idx = grp; }                 // packw 0..1023
  } else {
    role = (blockIdx.x < 2048) ? 1 : 2;
    idx = (role == 1) ? blockIdx.x : blockIdx.x - 2048;
  }

  if (role == 1) {  // ---- cvtx: x fp32 -> f16 ----
    const int i = idx * 256 + t;
    const float4 a = ((const float4*)x)[i * 2];
    const float4 b = ((const float4*)x)[i * 2 + 1];
    ((half8*)xh)[i] = cvt8(a, b);
    return;
  }

  if (role == 2) {  // ---- packw: 64x64 LDS tile transpose ----
    const int z = idx >> 8, rem2 = idx & 255;
    const int n0 = (rem2 >> 4) * 64, k0 = (rem2 & 15) * 64;
    const float* src = (z == 0) ? Wq : (z == 1) ? Wk : (z == 2) ? Wv : Wo;
#pragma unroll
    for (int i = 0; i < 4; ++i) {
      const int u = i * 256 + t;
      const int r = u >> 4, c4 = (u & 15) * 4;
      const float4 v = *(const float4*)(src + (size_t)(k0 + r) * DD + n0 + c4);
      Tl[(c4 + 0) * 72 + r] = (_Float16)v.x;
      Tl[(c4 + 1) * 72 + r] = (_Float16)v.y;
      Tl[(c4 + 2) * 72 + r] = (_Float16)v.z;
      Tl[(c4 + 3) * 72 + r] = (_Float16)v.w;
    }
    __syncthreads();
    _Float16* dst = Wt + (size_t)z * DD * DD;
#pragma unroll
    for (int i = 0; i < 2; ++i) {
      const int u = i * 256 + t;
      const int nr = u >> 3, ks = u & 7;
      const half8 hv = *(const half8*)&Tl[nr * 72 + ks * 8];
      *(half8*)(dst + (size_t)(n0 + nr) * DD + k0 + ks * 8) = hv;
    }
    return;
  }

  if constexpr (PRE) {  // ---- biasprep: 4 keys/thread, 16 heads, fp8 out ----
    const int r = idx;                 // 0..4095 = (b,q)
    const int b = r >> 10;             // 0..3
    const int q = r & 1023;            // full q row per block
    const int k4 = t * 4;              // 4 consecutive keys per thread
    if (t < GD * NH) wgL[t] = Wg[t];
    if (t < NH) wgL[GD * NH + t] = bg[t];

    const float* gp = geom + ((size_t)b * SS + q) * SS * GD + (size_t)k4 * GD;
    float4 gv[7];  // 4 keys x 7 features = 28 floats
#pragma unroll
    for (int i = 0; i < 7; ++i) gv[i] = *(const float4*)(gp + i * 4);
    float gf[28];
#pragma unroll
    for (int i = 0; i < 7; ++i) {
      gf[i * 4 + 0] = gv[i].x;
      gf[i * 4 + 1] = gv[i].y;
      gf[i * 4 + 2] = gv[i].z;
      gf[i * 4 + 3] = gv[i].w;
    }

    const int4 m4 = *(const int4*)(mask + b * SS + k4);
    const int mk[4] = {m4.x, m4.y, m4.z, m4.w};

    __syncthreads();

    unsigned char* dst = bias8 + ((size_t)b * NH * SS + q) * SS + k4;
#pragma unroll
    for (int h = 0; h < NH; ++h) {
      float wg[GD];
#pragma unroll
      for (int g = 0; g < GD; ++g) wg[g] = wgL[g * NH + h];  // broadcast reads
      const float bgh = wgL[GD * NH + h];
      float bi[4];
#pragma unroll
      for (int k2 = 0; k2 < 4; ++k2) {
        float s = bgh;
#pragma unroll
        for (int g = 0; g < GD; ++g) s = fmaf(gf[k2 * GD + g], wg[g], s);
        bi[k2] = mk[k2] ? s : -100.f;
      }
      int w0 = 0;
      w0 = __builtin_amdgcn_cvt_pk_fp8_f32(bi[0], bi[1], w0, false);
      w0 = __builtin_amdgcn_cvt_pk_fp8_f32(bi[2], bi[3], w0, true);
      *(unsigned*)(dst + (size_t)h * SS * SS) = (unsigned)w0;
    }
  }
}

// ---------------------------------------------------------------------------
// gemmQKV: standalone QKV hgemm, 768 blocks (3 per CU), m97 structure.
// XCD-bijective swizzle (768 % 8 == 0).
// ---------------------------------------------------------------------------
__global__ __launch_bounds__(256) void gemmQKV(const _Float16* __restrict__ A,
                                               const _Float16* __restrict__ Bt,
                                               const float* __restrict__ bq,
                                               const float* __restrict__ bk,
                                               const float* __restrict__ bv,
                                               _Float16* __restrict__ Oq,
                                               _Float16* __restrict__ Ok,
                                               _Float16* __restrict__ Ov) {
  __shared__ _Float16 Als[128 * 64];  // [m][k] linear, XOR-swizzled segs
  __shared__ _Float16 Bls[128 * 64];  // [n][k]
  const int t = threadIdx.x;
  const int raw = blockIdx.x;
  const int idx = (raw & 7) * 96 + (raw >> 3);  // bijective XCD chunking
  const int w = t >> 6, lane = t & 63, quad = lane >> 4, col = lane & 15;
  const int m0 = (idx & 31) * 128, n0 = (idx >> 5) * 128;
  const int mw = (w >> 1) * 64, nw = (w & 1) * 64;
  const int lr = lane >> 3, ls = lane & 7;
  const int swz8 = (ls ^ lr) * 8;  // pre-swizzled k-seg (halfs)
  const floatx4 zero4 = {0.f, 0.f, 0.f, 0.f};
  floatx4 acc[4][4];
#pragma unroll
  for (int i = 0; i < 4; ++i)
#pragma unroll
    for (int j = 0; j < 4; ++j) acc[i][j] = zero4;

  const _Float16* aBase = A + (size_t)(m0 + lr) * DD + swz8;
  const _Float16* bBase = Bt + (size_t)(n0 + lr) * DD + swz8;

  for (int k0 = 0; k0 < DD; k0 += 64) {
#pragma unroll
    for (int it = 0; it < 4; ++it) {
      const int rb = it * 32 + w * 8;
      async_cp16(aBase + (size_t)rb * DD + k0, &Als[rb * 64]);
      async_cp16(bBase + (size_t)rb * DD + k0, &Bls[rb * 64]);
    }
    __syncthreads();
#pragma unroll
    for (int kk = 0; kk < 2; ++kk) {
      half8 af[4], bf[4];
      const int sz = ((quad + kk * 4) ^ (col & 7)) * 8;
#pragma unroll
      for (int i = 0; i < 4; ++i)
        af[i] = *(const half8*)&Als[(mw + i * 16 + col) * 64 + sz];
#pragma unroll
      for (int j = 0; j < 4; ++j)
        bf[j] = *(const half8*)&Bls[(nw + j * 16 + col) * 64 + sz];
#pragma unroll
      for (int i = 0; i < 4; ++i)
#pragma unroll
        for (int j = 0; j < 4; ++j)
          acc[i][j] =
              __builtin_amdgcn_mfma_f32_16x16x32_f16(af[i], bf[j], acc[i][j], 0, 0, 0);
    }
    __syncthreads();
  }

#pragma unroll
  for (int j = 0; j < 4; ++j) {
    const int n = n0 + nw + j * 16 + col;
    const int which = n >> 10, hd = n & 1023;
    const int h = hd >> 6, d = hd & 63;
    const float* bp = (which == 0) ? bq : (which == 1) ? bk : bv;
    const float bias = bp[hd];
    _Float16* ob = (which == 0) ? Oq : (which == 1) ? Ok : Ov;
#pragma unroll
    for (int i = 0; i < 4; ++i) {
#pragma unroll
      for (int reg = 0; reg < 4; ++reg) {
        const int m = m0 + mw + i * 16 + quad * 4 + reg;
        const int b = m >> 10, s = m & 1023;
        ob[(((size_t)b * NH + h) * SS + s) * DK + d] = (_Float16)(acc[i][j][reg] + bias);
      }
    }
  }
}

// ---------------------------------------------------------------------------
// Out-projection hgemm: C[4096][1024] = ctxh @ Wt(o)^T + bo -> fp32 d_out
// ---------------------------------------------------------------------------
__global__ __launch_bounds__(256) void hgemm1(const _Float16* __restrict__ A,
                                              const _Float16* __restrict__ Bt,
                                              const float* __restrict__ b0,
                                              float* __restrict__ Of) {
  __shared__ _Float16 Als[128 * 64];
  __shared__ _Float16 Bls[128 * 64];
  const int t = threadIdx.x;
  const int w = t >> 6, lane = t & 63, quad = lane >> 4, col = lane & 15;
  const int m0 = blockIdx.x * 128, n0 = blockIdx.y * 128;
  const int mw = (w >> 1) * 64, nw = (w & 1) * 64;
  const int lr = lane >> 3, ls = lane & 7;
  const int swz8 = (ls ^ lr) * 8;
  const floatx4 zero4 = {0.f, 0.f, 0.f, 0.f};
  floatx4 acc[4][4];
#pragma unroll
  for (int i = 0; i < 4; ++i)
#pragma unroll
    for (int j = 0; j < 4; ++j) acc[i][j] = zero4;

  const _Float16* aBase = A + (size_t)(m0 + lr) * DD + swz8;
  const _Float16* bBase = Bt + (size_t)(n0 + lr) * DD + swz8;

  for (int k0 = 0; k0 < DD; k0 += 64) {
#pragma unroll
    for (int it = 0; it < 4; ++it) {
      const int rb = it * 32 + w * 8;
      async_cp16(aBase + (size_t)rb * DD + k0, &Als[rb * 64]);
      async_cp16(bBase + (size_t)rb * DD + k0, &Bls[rb * 64]);
    }
    __syncthreads();
#pragma unroll
    for (int kk = 0; kk < 2; ++kk) {
      half8 af[4], bf[4];
      const int sz = ((quad + kk * 4) ^ (col & 7)) * 8;
#pragma unroll
      for (int i = 0; i < 4; ++i) af[i] = *(const half8*)&Als[(mw + i * 16 + col) * 64 + sz];
#pragma unroll
      for (int j = 0; j < 4; ++j) bf[j] = *(const half8*)&Bls[(nw + j * 16 + col) * 64 + sz];
#pragma unroll
      for (int i = 0; i < 4; ++i)
#pragma unroll
        for (int j = 0; j < 4; ++j)
          acc[i][j] = __builtin_amdgcn_mfma_f32_16x16x32_f16(af[i], bf[j], acc[i][j], 0, 0, 0);
    }
    __syncthreads();
  }

#pragma unroll
  for (int j = 0; j < 4; ++j) {
    const int n = n0 + nw + j * 16 + col;
    const float bias = b0[n];
#pragma unroll
    for (int i = 0; i < 4; ++i) {
#pragma unroll
      for (int reg = 0; reg < 4; ++reg) {
        const int m = m0 + mw + i * 16 + quad * 4 + reg;
        Of[(size_t)m * DD + n] = acc[i][j][reg] + bias;
      }
    }
  }
}

// ---------------------------------------------------------------------------
// attnP: pipelined MFMA flash attention (PREBIAS only), swapped-operand layout.
// Grid (qt, h, b): consecutive blocks share K/V -> L2 hits on K DMA/V prefetch.
// Q loaded directly to registers (no LDS staging).
// bias8 prefetched TWO chunks ahead (named bregA/bregB, static indexing).
// Per sub-chunk: sync; issue K(c+1) DMA; commit V(c)/bias(c) regs->LDS;
// lgkmcnt(0)+s_barrier (no vmcnt drain); prefetch V(c+1)/bias(c+2); compute c.
// ---------------------------------------------------------------------------
__global__ __launch_bounds__(256) void attnP(const _Float16* __restrict__ Q,
                                             const _Float16* __restrict__ K,
                                             const _Float16* __restrict__ V,
                                             const unsigned char* __restrict__ bias8,
                                             _Float16* __restrict__ ctxbuf) {
  __shared__ _Float16 Ks0[64 * 64];          // K chunk buffer A (swizzled)
  __shared__ _Float16 Ks1[64 * 64];          // K chunk buffer B
  __shared__ _Float16 Vt[64 * 72];           // V^T chunk [dim][perm-key]
  __shared__ unsigned char biasL[64 * 80];   // fp8 bias chunk

  const int t = threadIdx.x;
  const int w = t >> 6, lane = t & 63, quad = lane >> 4, col = lane & 15;
  const int qt = blockIdx.x, h = blockIdx.y, b = blockIdx.z;
  const int q0 = qt * 64;
  const size_t bh = (size_t)b * NH + h;
  const _Float16* Qb = Q + bh * SS * DK;
  const _Float16* Kb = K + bh * SS * DK;
  const _Float16* Vb = V + bh * SS * DK;
  const unsigned char* bb8 = bias8 + (bh * SS + q0) * SS;

  const int lr = lane >> 3, ls = lane & 7;
  const int swz8 = (ls ^ lr) * 8;

  // V^T column permutation: key a -> column c(a)
  const int kg = (t >> 4) * 4, dg = (t & 15) * 4;
  const int cg = (kg & 0x20) | ((kg & 0x0C) << 1) | ((kg & 0x10) >> 2);
  const int brow = t >> 2, bseg = (t & 3) * 16;

  // ---- prologue: K0 DMA; V0/bias0/bias1 reg prefetch; Q direct to regs ----
#pragma unroll
  for (int it = 0; it < 2; ++it) {
    const int rb = it * 32 + w * 8;
    async_cp16(Kb + (size_t)(rb + lr) * DK + swz8, &Ks0[rb * 64]);
  }
  half4v vreg[4];
#pragma unroll
  for (int e = 0; e < 4; ++e)
    vreg[e] = *(const half4v*)(Vb + (size_t)(kg + e) * DK + dg);
  uint4 bregA = *(const uint4*)(bb8 + (size_t)brow * SS + bseg);
  uint4 bregB = *(const uint4*)(bb8 + (size_t)brow * SS + 64 + bseg);

  half8 qfrag[2];
  {
    const int qrow = w * 16 + col;
#pragma unroll
    for (int kk = 0; kk < 2; ++kk)
      qfrag[kk] = *(const half8*)(Qb + (size_t)(q0 + qrow) * DK + (quad + kk * 4) * 8);
  }

  const floatx4 zero4 = {0.f, 0.f, 0.f, 0.f};
  floatx4 ctx[4] = {zero4, zero4, zero4, zero4};
  float lsum = 0.f;

  auto subchunk = [&](int c_, _Float16* KsC, _Float16* KsN, uint4& brg) {
    __syncthreads();  // drains K(c) DMA + V(c)/bias prefetch; fences prev reads

    if (c_ < 15) {  // issue next K chunk DMA (stays in flight across compute)
#pragma unroll
      for (int it = 0; it < 2; ++it) {
        const int rb = it * 32 + w * 8;
        async_cp16(Kb + (size_t)((c_ + 1) * 64 + rb + lr) * DK + swz8,
                   &KsN[rb * 64]);
      }
    }
    // commit V(c) regs -> Vt (permuted columns), bias(c) reg -> biasL
#pragma unroll
    for (int i = 0; i < 4; ++i) {
      half4v hv = {vreg[0][i], vreg[1][i], vreg[2][i], vreg[3][i]};
      *(half4v*)&Vt[(dg + i) * 72 + cg] = hv;
    }
    *(uint4*)&biasL[brow * 80 + bseg] = brg;

    asm volatile("s_waitcnt lgkmcnt(0)" ::: "memory");
    __builtin_amdgcn_s_barrier();
    __builtin_amdgcn_sched_barrier(0);

    if (c_ < 15) {  // prefetch V(c+1), bias(c+2) under compute
      const int kn = (c_ + 1) * 64;
#pragma unroll
      for (int e = 0; e < 4; ++e)
        vreg[e] = *(const half4v*)(Vb + (size_t)(kn + kg + e) * DK + dg);
      const int kb2 = ((c_ + 2 < 16) ? (c_ + 2) : 15) * 64;
      brg = *(const uint4*)(bb8 + (size_t)brow * SS + kb2 + bseg);
    }
    __builtin_amdgcn_sched_barrier(0);

    // ---- QK^T SWAPPED: sc[nt][reg] = S[key = nt*16+quad*4+reg][q = col] ----
    floatx4 sc[4] = {zero4, zero4, zero4, zero4};
#pragma unroll
    for (int nt = 0; nt < 4; ++nt) {
      const int key = nt * 16 + col;
#pragma unroll
      for (int kk = 0; kk < 2; ++kk) {
        const half8 kf =
            *(const half8*)&KsC[key * 64 + (((quad + kk * 4) ^ (col & 7)) * 8)];
        sc[nt] = __builtin_amdgcn_mfma_f32_16x16x32_f16(kf, qfrag[kk], sc[nt], 0, 0, 0);
      }
    }

    // ---- p = exp(s/8 + bias); bias: one u32 per nt, literal-sel converts ----
    float ps[4][4];
#pragma unroll
    for (int nt = 0; nt < 4; ++nt) {
      const unsigned bw =
          *(const unsigned*)&biasL[(w * 16 + col) * 80 + nt * 16 + quad * 4];
      float bias4[4];
      bias4[0] = __builtin_amdgcn_cvt_f32_fp8((int)bw, 0);
      bias4[1] = __builtin_amdgcn_cvt_f32_fp8((int)bw, 1);
      bias4[2] = __builtin_amdgcn_cvt_f32_fp8((int)bw, 2);
      bias4[3] = __builtin_amdgcn_cvt_f32_fp8((int)bw, 3);
#pragma unroll
      for (int reg = 0; reg < 4; ++reg) {
        const float s = fmaf(sc[nt][reg], 0.125f, bias4[reg]);
        const float p = __expf(s);
        lsum += p;
        ps[nt][reg] = p;
      }
    }

    // ---- PV: B-operand is LANE-LOCAL (keys match permuted V^T columns) ----
#pragma unroll
    for (int kk = 0; kk < 2; ++kk) {
      half8 pf;
      pf[0] = (_Float16)ps[2 * kk][0];
      pf[1] = (_Float16)ps[2 * kk][1];
      pf[2] = (_Float16)ps[2 * kk][2];
      pf[3] = (_Float16)ps[2 * kk][3];
      pf[4] = (_Float16)ps[2 * kk + 1][0];
      pf[5] = (_Float16)ps[2 * kk + 1][1];
      pf[6] = (_Float16)ps[2 * kk + 1][2];
      pf[7] = (_Float16)ps[2 * kk + 1][3];
#pragma unroll
      for (int nt = 0; nt < 4; ++nt) {
        const half8 vb = *(const half8*)&Vt[(nt * 16 + col) * 72 + quad * 8 + kk * 32];
        ctx[nt] = __builtin_amdgcn_mfma_f32_16x16x32_f16(vb, pf, ctx[nt], 0, 0, 0);
      }
    }
  };

  for (int cp = 0; cp < 8; ++cp) {
    subchunk(2 * cp, Ks0, Ks1, bregA);
    subchunk(2 * cp + 1, Ks1, Ks0, bregB);
  }

  float l = lsum;
  l += __shfl_xor(l, 16, 64);
  l += __shfl_xor(l, 32, 64);
  const float inv = 1.f / l;

  _Float16* op = ctxbuf + ((size_t)b * SS + q0 + w * 16 + col) * DD + h * DK + quad * 4;
#pragma unroll
  for (int nt = 0; nt < 4; ++nt) {
    half4v o;
#pragma unroll
    for (int reg = 0; reg < 4; ++reg) o[reg] = (_Float16)(ctx[nt][reg] * inv);
    *(half4v*)(op + nt * 16) = o;
  }
}

// ---------------------------------------------------------------------------
// attn fallback (!prebias): inline geom bias, previous working structure.
// ---------------------------------------------------------------------------
__global__ __launch_bounds__(256) void attnF(const _Float16* __restrict__ Q,
                                             const _Float16* __restrict__ K,
                                             const _Float16* __restrict__ V,
                                             const float* __restrict__ geom,
                                             const int* __restrict__ mask,
                                             const float* __restrict__ Wg,
                                             const float* __restrict__ bg,
                                             _Float16* __restrict__ ctxbuf) {
  __shared__ _Float16 Ks[64 * 64];
  __shared__ _Float16 Vt[64 * 72];
  __shared__ _Float16 biasLf[64 * 72];
  __shared__ unsigned char mskL[SS];

  const int t = threadIdx.x;
  const int w = t >> 6, lane = t & 63, quad = lane >> 4, col = lane & 15;
  const int h = blockIdx.x, qt = blockIdx.y, b = blockIdx.z;
  const int q0 = qt * 64;
  const size_t bh = (size_t)b * NH + h;
  const _Float16* Qb = Q + bh * SS * DK;
  const _Float16* Kb = K + bh * SS * DK;
  const _Float16* Vb = V + bh * SS * DK;

  const int lr = lane >> 3, ls = lane & 7;
  const int swz8 = (ls ^ lr) * 8;

#pragma unroll
  for (int it = 0; it < 2; ++it) {
    const int rb = it * 32 + w * 8;
    async_cp16(Qb + (size_t)(q0 + rb + lr) * DK + swz8, &Ks[rb * 64]);
  }
  {
    const int4 m4 = *(const int4*)(mask + b * SS + t * 4);
    mskL[t * 4 + 0] = m4.x != 0;
    mskL[t * 4 + 1] = m4.y != 0;
    mskL[t * 4 + 2] = m4.z != 0;
    mskL[t * 4 + 3] = m4.w != 0;
  }
  __syncthreads();
  half8 qfrag[2];
  {
    const int qrow = w * 16 + col;
#pragma unroll
    for (int kk = 0; kk < 2; ++kk)
      qfrag[kk] = *(const half8*)&Ks[qrow * 64 + (((quad + kk * 4) ^ (col & 7)) * 8)];
  }

  float wgv[GD];
#pragma unroll
  for (int g = 0; g < GD; ++g) wgv[g] = Wg[g * NH + h];
  const float bgh = bg[h];
  const float* gptr = geom + (((size_t)b * SS + (q0 + (t >> 2))) * SS + (t & 3) * 16) * GD;

  const floatx4 zero4 = {0.f, 0.f, 0.f, 0.f};
  floatx4 ctx[4] = {zero4, zero4, zero4, zero4};
  float lsum = 0.f;

  const int kg = (t >> 4) * 4, dg = (t & 15) * 4;
  const int cg = (kg & 0x20) | ((kg & 0x0C) << 1) | ((kg & 0x10) >> 2);

  for (int c = 0; c < 16; ++c) {
    const int k0c = c * 64;
    __syncthreads();

#pragma unroll
    for (int it = 0; it < 2; ++it) {
      const int rb = it * 32 + w * 8;
      async_cp16(Kb + (size_t)(k0c + rb + lr) * DK + swz8, &Ks[rb * 64]);
    }
    {
      half4v f[4];
#pragma unroll
      for (int e = 0; e < 4; ++e)
        f[e] = *(const half4v*)(Vb + (size_t)(k0c + kg + e) * DK + dg);
#pragma unroll
      for (int i = 0; i < 4; ++i) {
        half4v hv = {f[0][i], f[1][i], f[2][i], f[3][i]};
        *(half4v*)&Vt[(dg + i) * 72 + cg] = hv;
      }
    }
    {
      const int gq = t >> 2, gk = (t & 3) * 16;
#pragma unroll
      for (int sg = 0; sg < 4; ++sg) {
        float4 gvv[7];
#pragma unroll
        for (int i7 = 0; i7 < 7; ++i7) gvv[i7] = *(const float4*)(gptr + sg * 28 + i7 * 4);
        const float* gf = (const float*)gvv;
        half4v bv;
#pragma unroll
        for (int k2 = 0; k2 < 4; ++k2) {
          float bi = bgh;
#pragma unroll
          for (int g = 0; g < GD; ++g) bi = fmaf(gf[k2 * GD + g], wgv[g], bi);
          bv[k2] = mskL[k0c + gk + sg * 4 + k2] ? (_Float16)bi : (_Float16)(-100.f);
        }
        *(half4v*)&biasLf[gq * 72 + gk + sg * 4] = bv;
      }
      gptr += 64 * GD;
    }
    __syncthreads();

    floatx4 sc[4] = {zero4, zero4, zero4, zero4};
#pragma unroll
    for (int nt = 0; nt < 4; ++nt) {
      const int key = nt * 16 + col;
#pragma unroll
      for (int kk = 0; kk < 2; ++kk) {
        const half8 kf = *(const half8*)&Ks[key * 64 + (((quad + kk * 4) ^ (col & 7)) * 8)];
        sc[nt] = __builtin_amdgcn_mfma_f32_16x16x32_f16(kf, qfrag[kk], sc[nt], 0, 0, 0);
      }
    }

    float ps[4][4];
#pragma unroll
    for (int nt = 0; nt < 4; ++nt) {
#pragma unroll
      for (int reg = 0; reg < 4; ++reg) {
        const float bias = (float)biasLf[(w * 16 + col) * 72 + nt * 16 + quad * 4 + reg];
        const float s = fmaf(sc[nt][reg], 0.125f, bias);
        const float p = __expf(s);
        lsum += p;
        ps[nt][reg] = p;
      }
    }

#pragma unroll
    for (int kk = 0; kk < 2; ++kk) {
      half8 pf;
      pf[0] = (_Float16)ps[2 * kk][0];
      pf[1] = (_Float16)ps[2 * kk][1];
      pf[2] = (_Float16)ps[2 * kk][2];
      pf[3] = (_Float16)ps[2 * kk][3];
      pf[4] = (_Float16)ps[2 * kk + 1][0];
      pf[5] = (_Float16)ps[2 * kk + 1][1];
      pf[6] = (_Float16)ps[2 * kk + 1][2];
      pf[7] = (_Float16)ps[2 * kk + 1][3];
#pragma unroll
      for (int nt = 0; nt < 4; ++nt) {
        const half8 vb = *(const half8*)&Vt[(nt * 16 + col) * 72 + quad * 8 + kk * 32];
        ctx[nt] = __builtin_amdgcn_mfma_f32_16x16x32_f16(vb, pf, ctx[nt], 0, 0, 0);
      }
    }
  }

  float l = lsum;
  l += __shfl_xor(l, 16, 64);
  l += __shfl_xor(l, 32, 64);
  const float inv = 1.f / l;

  _Float16* op = ctxbuf + ((size_t)b * SS + q0 + w * 16 + col) * DD + h * DK + quad * 4;
#pragma unroll
  for (int nt = 0; nt < 4; ++nt) {
    half4v o;
#pragma unroll
    for (int reg = 0; reg < 4; ++reg) o[reg] = (_Float16)(ctx[nt][reg] * inv);
    *(half4v*)(op + nt * 16) = o;
  }
}

// ---------------------------------------------------------------------------
extern "C" void kernel_launch(void* const* d_in, const int* in_sizes, int n_in,
                              void* d_out, int out_size, void* d_ws, size_t ws_size,
                              hipStream_t stream) {
  const float* x    = (const float*)d_in[0];
  const float* geom = (const float*)d_in[1];
  const int*   mask = (const int*)d_in[2];
  const float* Wq   = (const float*)d_in[3];
  const float* bq   = (const float*)d_in[4];
  const float* Wk   = (const float*)d_in[5];
  const float* bk   = (const float*)d_in[6];
  const float* Wv   = (const float*)d_in[7];
  const float* bv   = (const float*)d_in[8];
  const float* Wo   = (const float*)d_in[9];
  const float* bo   = (const float*)d_in[10];
  const float* Wg   = (const float*)d_in[11];
  const float* bg   = (const float*)d_in[12];
  float* out = (float*)d_out;

  const size_t NEL = (size_t)BB * SS * DD;  // 4,194,304
  char* p = (char*)d_ws;
  _Float16* xh   = (_Float16*)p;            p += NEL * 2;
  _Float16* Wt   = (_Float16*)p;            p += NEL * 2;
  _Float16* Qh   = (_Float16*)p;            p += NEL * 2;
  _Float16* Kh   = (_Float16*)p;            p += NEL * 2;
  _Float16* Vh   = (_Float16*)p;            p += NEL * 2;
  _Float16* ctxh = (_Float16*)p;            p += NEL * 2;       // 48 MiB base
  unsigned char* bias8 = (unsigned char*)p;                     // +64 MiB (fp8)
  const size_t need = (size_t)48 * 1024 * 1024 + (size_t)BB * NH * SS * SS;
  const bool prebias = ws_size >= need;

  if (prebias) {
    prep2<true><<<7168, 256, 0, stream>>>(x, xh, Wq, Wk, Wv, Wo, Wt,
                                          geom, mask, Wg, bg, bias8);
    gemmQKV<<<768, 256, 0, stream>>>(xh, Wt, bq, bk, bv, Qh, Kh, Vh);
    attnP<<<dim3(SS / 64, NH, BB), 256, 0, stream>>>(Qh, Kh, Vh, bias8, ctxh);
  } else {
    prep2<false><<<3072, 256, 0, stream>>>(x, xh, Wq, Wk, Wv, Wo, Wt,
                                           geom, mask, Wg, bg, nullptr);
    gemmQKV<<<768, 256, 0, stream>>>(xh, Wt, bq, bk, bv, Qh, Kh, Vh);
    attnF<<<dim3(NH, SS / 64, BB), 256, 0, stream>>>(Qh, Kh, Vh, geom, mask, Wg, bg, ctxh);
  }

  hgemm1<<<dim3(32, 8), 256, 0, stream>>>(ctxh, Wt + (size_t)3 * DD * DD, bo, out);
}

// Round 7
// 324.258 us; speedup vs baseline: 1.0232x; 1.0232x over previous
//
#include <hip/hip_runtime.h>
#include <hip/hip_bf16.h>
#include <math.h>

// Problem constants (StructureGuidedAttention: B=4, S=1024, D=1024, H=16, dk=64, G=7)
#define BB 4
#define SS 1024
#define DD 1024
#define NH 16
#define DK 64
#define GD 7

typedef _Float16 half8 __attribute__((ext_vector_type(8)));
typedef _Float16 half4v __attribute__((ext_vector_type(4)));
typedef float floatx4 __attribute__((ext_vector_type(4)));

// async global->LDS 16B DMA. Dest is wave-uniform base + lane*16 (linear);
// swizzling is done by PRE-SWIZZLING the per-lane global source address.
__device__ __forceinline__ void async_cp16(const void* g, void* l) {
  __builtin_amdgcn_global_load_lds(
      (const __attribute__((address_space(1))) void*)g,
      (__attribute__((address_space(3))) void*)l, 16, 0, 0);
}

__device__ inline half8 cvt8(const float4 a, const float4 b) {
  half8 h;
  h[0] = (_Float16)a.x; h[1] = (_Float16)a.y; h[2] = (_Float16)a.z; h[3] = (_Float16)a.w;
  h[4] = (_Float16)b.x; h[5] = (_Float16)b.y; h[6] = (_Float16)b.z; h[7] = (_Float16)b.w;
  return h;
}

// ---------------------------------------------------------------------------
// prep2: merged streaming pass. PRE=true: 7168 blocks, roles interleaved
// 4:2:1 (biasprep : cvtx : packw); PRE=false: 3072 blocks, cvtx + packw only.
// biasprep-T: transaction-shaped. Rounds 4-6 showed the old biasprep was
// latency/transaction-bound (112B-lane-stride loads = 64 cachelines/instr,
// 4B strided stores). Now: coalesced global_load_lds staging of the geom row,
// conflict-free LDS reads (key = s*256+t, stride 7 coprime 32), LDS byte
// transpose, and 1KB/wave coalesced uint4 stores.
// ---------------------------------------------------------------------------
template <bool PRE>
__global__ __launch_bounds__(256) void prep2(const float* __restrict__ x,
                                             _Float16* __restrict__ xh,
                                             const float* __restrict__ Wq,
                                             const float* __restrict__ Wk,
                                             const float* __restrict__ Wv,
                                             const float* __restrict__ Wo,
                                             _Float16* __restrict__ Wt,
                                             const float* __restrict__ geom,
                                             const int* __restrict__ mask,
                                             const float* __restrict__ Wg,
                                             const float* __restrict__ bg,
                                             unsigned char* __restrict__ bias8) {
  __shared__ char shBuf[28672];          // geom row (28KB) | packw Tl | result bytes
  __shared__ float wgL[GD * NH + NH];    // biasprep weights
  const int t = threadIdx.x;
  int role, idx;
  if (PRE) {
    const int grp = blockIdx.x / 7, rem = blockIdx.x % 7;  // 7168 = 7*1024
    if (rem < 4)      { role = 0; idx = grp * 4 + rem; }       // biasprep 0..4095
    else if (rem < 6) { role = 1; idx = grp * 2 + rem - 4; }   // cvtx 0..2047
    else              { role = 2; idx = grp; }                 // packw 0..1023
  } else {
    role = (blockIdx.x < 2048) ? 1 : 2;
    idx = (role == 1) ? blockIdx.x : blockIdx.x - 2048;
  }

  if (role == 1) {  // ---- cvtx: x fp32 -> f16 ----
    const int i = idx * 256 + t;
    const float4 a = ((const float4*)x)[i * 2];
    const float4 b = ((const float4*)x)[i * 2 + 1];
    ((half8*)xh)[i] = cvt8(a, b);
    return;
  }

  if (role == 2) {  // ---- packw: 64x64 LDS tile transpose ----
    _Float16* Tl = (_Float16*)shBuf;  // [64][72]
    const int z = idx >> 8, rem2 = idx & 255;
    const int n0 = (rem2 >> 4) * 64, k0 = (rem2 & 15) * 64;
    const float* src = (z == 0) ? Wq : (z == 1) ? Wk : (z == 2) ? Wv : Wo;
#pragma unroll
    for (int i = 0; i < 4; ++i) {
      const int u = i * 256 + t;
      const int r = u >> 4, c4 = (u & 15) * 4;
      const float4 v = *(const float4*)(src + (size_t)(k0 + r) * DD + n0 + c4);
      Tl[(c4 + 0) * 72 + r] = (_Float16)v.x;
      Tl[(c4 + 1) * 72 + r] = (_Float16)v.y;
      Tl[(c4 + 2) * 72 + r] = (_Float16)v.z;
      Tl[(c4 + 3) * 72 + r] = (_Float16)v.w;
    }
    __syncthreads();
    _Float16* dst = Wt + (size_t)z * DD * DD;
#pragma unroll
    for (int i = 0; i < 2; ++i) {
      const int u = i * 256 + t;
      const int nr = u >> 3, ks = u & 7;
      const half8 hv = *(const half8*)&Tl[nr * 72 + ks * 8];
      *(half8*)(dst + (size_t)(n0 + nr) * DD + k0 + ks * 8) = hv;
    }
    return;
  }

  if constexpr (PRE) {  // ---- biasprep-T ----
    const int r = idx;         // 0..4095 = (b,q)
    const int b = r >> 10;
    const int q = r & 1023;
    if (t < GD * NH) wgL[t] = Wg[t];
    if (t < NH) wgL[GD * NH + t] = bg[t];

    // 1) stage full geom row (1024 keys x 7 f32 = 28KB) via coalesced DMA
    const float* gr = geom + ((size_t)b * SS + q) * SS * GD;
    float* gL = (float*)shBuf;
#pragma unroll
    for (int i = 0; i < 7; ++i)
      async_cp16(gr + (size_t)(i * 256 + t) * 4, gL + (i * 256 + t) * 4);

    int mk0 = mask[b * SS + t];
    int mk1 = mask[b * SS + 256 + t];
    int mk2 = mask[b * SS + 512 + t];
    int mk3 = mask[b * SS + 768 + t];

    __syncthreads();  // drains DMA + wgL

    // 2) compute: thread t owns keys {t, 256+t, 512+t, 768+t}
    unsigned bph[16];
#pragma unroll
    for (int h = 0; h < 16; ++h) bph[h] = 0u;

    {  // key pair (s=0, s=1) -> bytes 0,1
      float gfA[7], gfB[7];
#pragma unroll
      for (int j = 0; j < 7; ++j) {
        gfA[j] = gL[t * 7 + j];             // bank (7t+j)%32: 2-way, free
        gfB[j] = gL[(256 + t) * 7 + j];
      }
#pragma unroll
      for (int h = 0; h < 16; ++h) {
        const float bgh = wgL[GD * NH + h];
        float a = bgh, c = bgh;
#pragma unroll
        for (int g = 0; g < GD; ++g) {
          const float wv = wgL[g * NH + h];
          a = fmaf(gfA[g], wv, a);
          c = fmaf(gfB[g], wv, c);
        }
        a = mk0 ? a : -100.f;
        c = mk1 ? c : -100.f;
        bph[h] = (unsigned)__builtin_amdgcn_cvt_pk_fp8_f32(a, c, (int)bph[h], false);
      }
    }
    {  // key pair (s=2, s=3) -> bytes 2,3
      float gfA[7], gfB[7];
#pragma unroll
      for (int j = 0; j < 7; ++j) {
        gfA[j] = gL[(512 + t) * 7 + j];
        gfB[j] = gL[(768 + t) * 7 + j];
      }
#pragma unroll
      for (int h = 0; h < 16; ++h) {
        const float bgh = wgL[GD * NH + h];
        float a = bgh, c = bgh;
#pragma unroll
        for (int g = 0; g < GD; ++g) {
          const float wv = wgL[g * NH + h];
          a = fmaf(gfA[g], wv, a);
          c = fmaf(gfB[g], wv, c);
        }
        a = mk2 ? a : -100.f;
        c = mk3 ? c : -100.f;
        bph[h] = (unsigned)__builtin_amdgcn_cvt_pk_fp8_f32(a, c, (int)bph[h], true);
      }
    }

    __syncthreads();  // gL reads done; reuse buffer as result bytes

    // 3) byte transpose into [h][1024k]
    unsigned char* rL = (unsigned char*)shBuf;
#pragma unroll
    for (int h = 0; h < 16; ++h) {
      rL[h * 1024 + t]       = (unsigned char)(bph[h]);
      rL[h * 1024 + 256 + t] = (unsigned char)(bph[h] >> 8);
      rL[h * 1024 + 512 + t] = (unsigned char)(bph[h] >> 16);
      rL[h * 1024 + 768 + t] = (unsigned char)(bph[h] >> 24);
    }
    __syncthreads();

    // 4) coalesced readout: wave wv stores h = i*4+wv, 1KB/wave/instr
    const int wv = t >> 6, ln = t & 63;
#pragma unroll
    for (int i = 0; i < 4; ++i) {
      const int h = i * 4 + wv;
      const uint4 v = *(const uint4*)&rL[h * 1024 + ln * 16];
      *(uint4*)(bias8 + (((size_t)b * NH + h) * SS + q) * SS + ln * 16) = v;
    }
  }
}

// ---------------------------------------------------------------------------
// gemmQKV: standalone QKV hgemm, 768 blocks (3 per CU), m97 structure.
// XCD-bijective swizzle (768 % 8 == 0).
// ---------------------------------------------------------------------------
__global__ __launch_bounds__(256) void gemmQKV(const _Float16* __restrict__ A,
                                               const _Float16* __restrict__ Bt,
                                               const float* __restrict__ bq,
                                               const float* __restrict__ bk,
                                               const float* __restrict__ bv,
                                               _Float16* __restrict__ Oq,
                                               _Float16* __restrict__ Ok,
                                               _Float16* __restrict__ Ov) {
  __shared__ _Float16 Als[128 * 64];  // [m][k] linear, XOR-swizzled segs
  __shared__ _Float16 Bls[128 * 64];  // [n][k]
  const int t = threadIdx.x;
  const int raw = blockIdx.x;
  const int idx = (raw & 7) * 96 + (raw >> 3);  // bijective XCD chunking
  const int w = t >> 6, lane = t & 63, quad = lane >> 4, col = lane & 15;
  const int m0 = (idx & 31) * 128, n0 = (idx >> 5) * 128;
  const int mw = (w >> 1) * 64, nw = (w & 1) * 64;
  const int lr = lane >> 3, ls = lane & 7;
  const int swz8 = (ls ^ lr) * 8;  // pre-swizzled k-seg (halfs)
  const floatx4 zero4 = {0.f, 0.f, 0.f, 0.f};
  floatx4 acc[4][4];
#pragma unroll
  for (int i = 0; i < 4; ++i)
#pragma unroll
    for (int j = 0; j < 4; ++j) acc[i][j] = zero4;

  const _Float16* aBase = A + (size_t)(m0 + lr) * DD + swz8;
  const _Float16* bBase = Bt + (size_t)(n0 + lr) * DD + swz8;

  for (int k0 = 0; k0 < DD; k0 += 64) {
#pragma unroll
    for (int it = 0; it < 4; ++it) {
      const int rb = it * 32 + w * 8;
      async_cp16(aBase + (size_t)rb * DD + k0, &Als[rb * 64]);
      async_cp16(bBase + (size_t)rb * DD + k0, &Bls[rb * 64]);
    }
    __syncthreads();
#pragma unroll
    for (int kk = 0; kk < 2; ++kk) {
      half8 af[4], bf[4];
      const int sz = ((quad + kk * 4) ^ (col & 7)) * 8;
#pragma unroll
      for (int i = 0; i < 4; ++i)
        af[i] = *(const half8*)&Als[(mw + i * 16 + col) * 64 + sz];
#pragma unroll
      for (int j = 0; j < 4; ++j)
        bf[j] = *(const half8*)&Bls[(nw + j * 16 + col) * 64 + sz];
#pragma unroll
      for (int i = 0; i < 4; ++i)
#pragma unroll
        for (int j = 0; j < 4; ++j)
          acc[i][j] =
              __builtin_amdgcn_mfma_f32_16x16x32_f16(af[i], bf[j], acc[i][j], 0, 0, 0);
    }
    __syncthreads();
  }

#pragma unroll
  for (int j = 0; j < 4; ++j) {
    const int n = n0 + nw + j * 16 + col;
    const int which = n >> 10, hd = n & 1023;
    const int h = hd >> 6, d = hd & 63;
    const float* bp = (which == 0) ? bq : (which == 1) ? bk : bv;
    const float bias = bp[hd];
    _Float16* ob = (which == 0) ? Oq : (which == 1) ? Ok : Ov;
#pragma unroll
    for (int i = 0; i < 4; ++i) {
#pragma unroll
      for (int reg = 0; reg < 4; ++reg) {
        const int m = m0 + mw + i * 16 + quad * 4 + reg;
        const int b = m >> 10, s = m & 1023;
        ob[(((size_t)b * NH + h) * SS + s) * DK + d] = (_Float16)(acc[i][j][reg] + bias);
      }
    }
  }
}

// ---------------------------------------------------------------------------
// Out-projection hgemm: C[4096][1024] = ctxh @ Wt(o)^T + bo -> fp32 d_out
// ---------------------------------------------------------------------------
__global__ __launch_bounds__(256) void hgemm1(const _Float16* __restrict__ A,
                                              const _Float16* __restrict__ Bt,
                                              const float* __restrict__ b0,
                                              float* __restrict__ Of) {
  __shared__ _Float16 Als[128 * 64];
  __shared__ _Float16 Bls[128 * 64];
  const int t = threadIdx.x;
  const int w = t >> 6, lane = t & 63, quad = lane >> 4, col = lane & 15;
  const int m0 = blockIdx.x * 128, n0 = blockIdx.y * 128;
  const int mw = (w >> 1) * 64, nw = (w & 1) * 64;
  const int lr = lane >> 3, ls = lane & 7;
  const int swz8 = (ls ^ lr) * 8;
  const floatx4 zero4 = {0.f, 0.f, 0.f, 0.f};
  floatx4 acc[4][4];
#pragma unroll
  for (int i = 0; i < 4; ++i)
#pragma unroll
    for (int j = 0; j < 4; ++j) acc[i][j] = zero4;

  const _Float16* aBase = A + (size_t)(m0 + lr) * DD + swz8;
  const _Float16* bBase = Bt + (size_t)(n0 + lr) * DD + swz8;

  for (int k0 = 0; k0 < DD; k0 += 64) {
#pragma unroll
    for (int it = 0; it < 4; ++it) {
      const int rb = it * 32 + w * 8;
      async_cp16(aBase + (size_t)rb * DD + k0, &Als[rb * 64]);
      async_cp16(bBase + (size_t)rb * DD + k0, &Bls[rb * 64]);
    }
    __syncthreads();
#pragma unroll
    for (int kk = 0; kk < 2; ++kk) {
      half8 af[4], bf[4];
      const int sz = ((quad + kk * 4) ^ (col & 7)) * 8;
#pragma unroll
      for (int i = 0; i < 4; ++i) af[i] = *(const half8*)&Als[(mw + i * 16 + col) * 64 + sz];
#pragma unroll
      for (int j = 0; j < 4; ++j) bf[j] = *(const half8*)&Bls[(nw + j * 16 + col) * 64 + sz];
#pragma unroll
      for (int i = 0; i < 4; ++i)
#pragma unroll
        for (int j = 0; j < 4; ++j)
          acc[i][j] = __builtin_amdgcn_mfma_f32_16x16x32_f16(af[i], bf[j], acc[i][j], 0, 0, 0);
    }
    __syncthreads();
  }

#pragma unroll
  for (int j = 0; j < 4; ++j) {
    const int n = n0 + nw + j * 16 + col;
    const float bias = b0[n];
#pragma unroll
    for (int i = 0; i < 4; ++i) {
#pragma unroll
      for (int reg = 0; reg < 4; ++reg) {
        const int m = m0 + mw + i * 16 + quad * 4 + reg;
        Of[(size_t)m * DD + n] = acc[i][j][reg] + bias;
      }
    }
  }
}

// ---------------------------------------------------------------------------
// attnP: pipelined MFMA flash attention (PREBIAS only), swapped-operand layout.
// Grid (qt, h, b): consecutive blocks share K/V -> L2 hits on K DMA/V prefetch.
// Q loaded directly to registers (no LDS staging).
// bias8 prefetched TWO chunks ahead (named bregA/bregB, static indexing).
// Per sub-chunk: sync; issue K(c+1) DMA; commit V(c)/bias(c) regs->LDS;
// lgkmcnt(0)+s_barrier (no vmcnt drain); prefetch V(c+1)/bias(c+2); compute c.
// ---------------------------------------------------------------------------
__global__ __launch_bounds__(256) void attnP(const _Float16* __restrict__ Q,
                                             const _Float16* __restrict__ K,
                                             const _Float16* __restrict__ V,
                                             const unsigned char* __restrict__ bias8,
                                             _Float16* __restrict__ ctxbuf) {
  __shared__ _Float16 Ks0[64 * 64];          // K chunk buffer A (swizzled)
  __shared__ _Float16 Ks1[64 * 64];          // K chunk buffer B
  __shared__ _Float16 Vt[64 * 72];           // V^T chunk [dim][perm-key]
  __shared__ unsigned char biasL[64 * 80];   // fp8 bias chunk

  const int t = threadIdx.x;
  const int w = t >> 6, lane = t & 63, quad = lane >> 4, col = lane & 15;
  const int qt = blockIdx.x, h = blockIdx.y, b = blockIdx.z;
  const int q0 = qt * 64;
  const size_t bh = (size_t)b * NH + h;
  const _Float16* Qb = Q + bh * SS * DK;
  const _Float16* Kb = K + bh * SS * DK;
  const _Float16* Vb = V + bh * SS * DK;
  const unsigned char* bb8 = bias8 + (bh * SS + q0) * SS;

  const int lr = lane >> 3, ls = lane & 7;
  const int swz8 = (ls ^ lr) * 8;

  // V^T column permutation: key a -> column c(a)
  const int kg = (t >> 4) * 4, dg = (t & 15) * 4;
  const int cg = (kg & 0x20) | ((kg & 0x0C) << 1) | ((kg & 0x10) >> 2);
  const int brow = t >> 2, bseg = (t & 3) * 16;

  // ---- prologue: K0 DMA; V0/bias0/bias1 reg prefetch; Q direct to regs ----
#pragma unroll
  for (int it = 0; it < 2; ++it) {
    const int rb = it * 32 + w * 8;
    async_cp16(Kb + (size_t)(rb + lr) * DK + swz8, &Ks0[rb * 64]);
  }
  half4v vreg[4];
#pragma unroll
  for (int e = 0; e < 4; ++e)
    vreg[e] = *(const half4v*)(Vb + (size_t)(kg + e) * DK + dg);
  uint4 bregA = *(const uint4*)(bb8 + (size_t)brow * SS + bseg);
  uint4 bregB = *(const uint4*)(bb8 + (size_t)brow * SS + 64 + bseg);

  half8 qfrag[2];
  {
    const int qrow = w * 16 + col;
#pragma unroll
    for (int kk = 0; kk < 2; ++kk)
      qfrag[kk] = *(const half8*)(Qb + (size_t)(q0 + qrow) * DK + (quad + kk * 4) * 8);
  }

  const floatx4 zero4 = {0.f, 0.f, 0.f, 0.f};
  floatx4 ctx[4] = {zero4, zero4, zero4, zero4};
  float lsum = 0.f;

  auto subchunk = [&](int c_, _Float16* KsC, _Float16* KsN, uint4& brg) {
    __syncthreads();  // drains K(c) DMA + V(c)/bias prefetch; fences prev reads

    if (c_ < 15) {  // issue next K chunk DMA (stays in flight across compute)
#pragma unroll
      for (int it = 0; it < 2; ++it) {
        const int rb = it * 32 + w * 8;
        async_cp16(Kb + (size_t)((c_ + 1) * 64 + rb + lr) * DK + swz8,
                   &KsN[rb * 64]);
      }
    }
    // commit V(c) regs -> Vt (permuted columns), bias(c) reg -> biasL
#pragma unroll
    for (int i = 0; i < 4; ++i) {
      half4v hv = {vreg[0][i], vreg[1][i], vreg[2][i], vreg[3][i]};
      *(half4v*)&Vt[(dg + i) * 72 + cg] = hv;
    }
    *(uint4*)&biasL[brow * 80 + bseg] = brg;

    asm volatile("s_waitcnt lgkmcnt(0)" ::: "memory");
    __builtin_amdgcn_s_barrier();
    __builtin_amdgcn_sched_barrier(0);

    if (c_ < 15) {  // prefetch V(c+1), bias(c+2) under compute
      const int kn = (c_ + 1) * 64;
#pragma unroll
      for (int e = 0; e < 4; ++e)
        vreg[e] = *(const half4v*)(Vb + (size_t)(kn + kg + e) * DK + dg);
      const int kb2 = ((c_ + 2 < 16) ? (c_ + 2) : 15) * 64;
      brg = *(const uint4*)(bb8 + (size_t)brow * SS + kb2 + bseg);
    }
    __builtin_amdgcn_sched_barrier(0);

    // ---- QK^T SWAPPED: sc[nt][reg] = S[key = nt*16+quad*4+reg][q = col] ----
    floatx4 sc[4] = {zero4, zero4, zero4, zero4};
#pragma unroll
    for (int nt = 0; nt < 4; ++nt) {
      const int key = nt * 16 + col;
#pragma unroll
      for (int kk = 0; kk < 2; ++kk) {
        const half8 kf =
            *(const half8*)&KsC[key * 64 + (((quad + kk * 4) ^ (col & 7)) * 8)];
        sc[nt] = __builtin_amdgcn_mfma_f32_16x16x32_f16(kf, qfrag[kk], sc[nt], 0, 0, 0);
      }
    }

    // ---- p = exp(s/8 + bias); bias: one u32 per nt, literal-sel converts ----
    float ps[4][4];
#pragma unroll
    for (int nt = 0; nt < 4; ++nt) {
      const unsigned bw =
          *(const unsigned*)&biasL[(w * 16 + col) * 80 + nt * 16 + quad * 4];
      float bias4[4];
      bias4[0] = __builtin_amdgcn_cvt_f32_fp8((int)bw, 0);
      bias4[1] = __builtin_amdgcn_cvt_f32_fp8((int)bw, 1);
      bias4[2] = __builtin_amdgcn_cvt_f32_fp8((int)bw, 2);
      bias4[3] = __builtin_amdgcn_cvt_f32_fp8((int)bw, 3);
#pragma unroll
      for (int reg = 0; reg < 4; ++reg) {
        const float s = fmaf(sc[nt][reg], 0.125f, bias4[reg]);
        const float p = __expf(s);
        lsum += p;
        ps[nt][reg] = p;
      }
    }

    // ---- PV: B-operand is LANE-LOCAL (keys match permuted V^T columns) ----
#pragma unroll
    for (int kk = 0; kk < 2; ++kk) {
      half8 pf;
      pf[0] = (_Float16)ps[2 * kk][0];
      pf[1] = (_Float16)ps[2 * kk][1];
      pf[2] = (_Float16)ps[2 * kk][2];
      pf[3] = (_Float16)ps[2 * kk][3];
      pf[4] = (_Float16)ps[2 * kk + 1][0];
      pf[5] = (_Float16)ps[2 * kk + 1][1];
      pf[6] = (_Float16)ps[2 * kk + 1][2];
      pf[7] = (_Float16)ps[2 * kk + 1][3];
#pragma unroll
      for (int nt = 0; nt < 4; ++nt) {
        const half8 vb = *(const half8*)&Vt[(nt * 16 + col) * 72 + quad * 8 + kk * 32];
        ctx[nt] = __builtin_amdgcn_mfma_f32_16x16x32_f16(vb, pf, ctx[nt], 0, 0, 0);
      }
    }
  };

  for (int cp = 0; cp < 8; ++cp) {
    subchunk(2 * cp, Ks0, Ks1, bregA);
    subchunk(2 * cp + 1, Ks1, Ks0, bregB);
  }

  float l = lsum;
  l += __shfl_xor(l, 16, 64);
  l += __shfl_xor(l, 32, 64);
  const float inv = 1.f / l;

  _Float16* op = ctxbuf + ((size_t)b * SS + q0 + w * 16 + col) * DD + h * DK + quad * 4;
#pragma unroll
  for (int nt = 0; nt < 4; ++nt) {
    half4v o;
#pragma unroll
    for (int reg = 0; reg < 4; ++reg) o[reg] = (_Float16)(ctx[nt][reg] * inv);
    *(half4v*)(op + nt * 16) = o;
  }
}

// ---------------------------------------------------------------------------
// attn fallback (!prebias): inline geom bias, previous working structure.
// ---------------------------------------------------------------------------
__global__ __launch_bounds__(256) void attnF(const _Float16* __restrict__ Q,
                                             const _Float16* __restrict__ K,
                                             const _Float16* __restrict__ V,
                                             const float* __restrict__ geom,
                                             const int* __restrict__ mask,
                                             const float* __restrict__ Wg,
                                             const float* __restrict__ bg,
                                             _Float16* __restrict__ ctxbuf) {
  __shared__ _Float16 Ks[64 * 64];
  __shared__ _Float16 Vt[64 * 72];
  __shared__ _Float16 biasLf[64 * 72];
  __shared__ unsigned char mskL[SS];

  const int t = threadIdx.x;
  const int w = t >> 6, lane = t & 63, quad = lane >> 4, col = lane & 15;
  const int h = blockIdx.x, qt = blockIdx.y, b = blockIdx.z;
  const int q0 = qt * 64;
  const size_t bh = (size_t)b * NH + h;
  const _Float16* Qb = Q + bh * SS * DK;
  const _Float16* Kb = K + bh * SS * DK;
  const _Float16* Vb = V + bh * SS * DK;

  const int lr = lane >> 3, ls = lane & 7;
  const int swz8 = (ls ^ lr) * 8;

#pragma unroll
  for (int it = 0; it < 2; ++it) {
    const int rb = it * 32 + w * 8;
    async_cp16(Qb + (size_t)(q0 + rb + lr) * DK + swz8, &Ks[rb * 64]);
  }
  {
    const int4 m4 = *(const int4*)(mask + b * SS + t * 4);
    mskL[t * 4 + 0] = m4.x != 0;
    mskL[t * 4 + 1] = m4.y != 0;
    mskL[t * 4 + 2] = m4.z != 0;
    mskL[t * 4 + 3] = m4.w != 0;
  }
  __syncthreads();
  half8 qfrag[2];
  {
    const int qrow = w * 16 + col;
#pragma unroll
    for (int kk = 0; kk < 2; ++kk)
      qfrag[kk] = *(const half8*)&Ks[qrow * 64 + (((quad + kk * 4) ^ (col & 7)) * 8)];
  }

  float wgv[GD];
#pragma unroll
  for (int g = 0; g < GD; ++g) wgv[g] = Wg[g * NH + h];
  const float bgh = bg[h];
  const float* gptr = geom + (((size_t)b * SS + (q0 + (t >> 2))) * SS + (t & 3) * 16) * GD;

  const floatx4 zero4 = {0.f, 0.f, 0.f, 0.f};
  floatx4 ctx[4] = {zero4, zero4, zero4, zero4};
  float lsum = 0.f;

  const int kg = (t >> 4) * 4, dg = (t & 15) * 4;
  const int cg = (kg & 0x20) | ((kg & 0x0C) << 1) | ((kg & 0x10) >> 2);

  for (int c = 0; c < 16; ++c) {
    const int k0c = c * 64;
    __syncthreads();

#pragma unroll
    for (int it = 0; it < 2; ++it) {
      const int rb = it * 32 + w * 8;
      async_cp16(Kb + (size_t)(k0c + rb + lr) * DK + swz8, &Ks[rb * 64]);
    }
    {
      half4v f[4];
#pragma unroll
      for (int e = 0; e < 4; ++e)
        f[e] = *(const half4v*)(Vb + (size_t)(k0c + kg + e) * DK + dg);
#pragma unroll
      for (int i = 0; i < 4; ++i) {
        half4v hv = {f[0][i], f[1][i], f[2][i], f[3][i]};
        *(half4v*)&Vt[(dg + i) * 72 + cg] = hv;
      }
    }
    {
      const int gq = t >> 2, gk = (t & 3) * 16;
#pragma unroll
      for (int sg = 0; sg < 4; ++sg) {
        float4 gvv[7];
#pragma unroll
        for (int i7 = 0; i7 < 7; ++i7) gvv[i7] = *(const float4*)(gptr + sg * 28 + i7 * 4);
        const float* gf = (const float*)gvv;
        half4v bv;
#pragma unroll
        for (int k2 = 0; k2 < 4; ++k2) {
          float bi = bgh;
#pragma unroll
          for (int g = 0; g < GD; ++g) bi = fmaf(gf[k2 * GD + g], wgv[g], bi);
          bv[k2] = mskL[k0c + gk + sg * 4 + k2] ? (_Float16)bi : (_Float16)(-100.f);
        }
        *(half4v*)&biasLf[gq * 72 + gk + sg * 4] = bv;
      }
      gptr += 64 * GD;
    }
    __syncthreads();

    floatx4 sc[4] = {zero4, zero4, zero4, zero4};
#pragma unroll
    for (int nt = 0; nt < 4; ++nt) {
      const int key = nt * 16 + col;
#pragma unroll
      for (int kk = 0; kk < 2; ++kk) {
        const half8 kf = *(const half8*)&Ks[key * 64 + (((quad + kk * 4) ^ (col & 7)) * 8)];
        sc[nt] = __builtin_amdgcn_mfma_f32_16x16x32_f16(kf, qfrag[kk], sc[nt], 0, 0, 0);
      }
    }

    float ps[4][4];
#pragma unroll
    for (int nt = 0; nt < 4; ++nt) {
#pragma unroll
      for (int reg = 0; reg < 4; ++reg) {
        const float bias = (float)biasLf[(w * 16 + col) * 72 + nt * 16 + quad * 4 + reg];
        const float s = fmaf(sc[nt][reg], 0.125f, bias);
        const float p = __expf(s);
        lsum += p;
        ps[nt][reg] = p;
      }
    }

#pragma unroll
    for (int kk = 0; kk < 2; ++kk) {
      half8 pf;
      pf[0] = (_Float16)ps[2 * kk][0];
      pf[1] = (_Float16)ps[2 * kk][1];
      pf[2] = (_Float16)ps[2 * kk][2];
      pf[3] = (_Float16)ps[2 * kk][3];
      pf[4] = (_Float16)ps[2 * kk + 1][0];
      pf[5] = (_Float16)ps[2 * kk + 1][1];
      pf[6] = (_Float16)ps[2 * kk + 1][2];
      pf[7] = (_Float16)ps[2 * kk + 1][3];
#pragma unroll
      for (int nt = 0; nt < 4; ++nt) {
        const half8 vb = *(const half8*)&Vt[(nt * 16 + col) * 72 + quad * 8 + kk * 32];
        ctx[nt] = __builtin_amdgcn_mfma_f32_16x16x32_f16(vb, pf, ctx[nt], 0, 0, 0);
      }
    }
  }

  float l = lsum;
  l += __shfl_xor(l, 16, 64);
  l += __shfl_xor(l, 32, 64);
  const float inv = 1.f / l;

  _Float16* op = ctxbuf + ((size_t)b * SS + q0 + w * 16 + col) * DD + h * DK + quad * 4;
#pragma unroll
  for (int nt = 0; nt < 4; ++nt) {
    half4v o;
#pragma unroll
    for (int reg = 0; reg < 4; ++reg) o[reg] = (_Float16)(ctx[nt][reg] * inv);
    *(half4v*)(op + nt * 16) = o;
  }
}

// ---------------------------------------------------------------------------
extern "C" void kernel_launch(void* const* d_in, const int* in_sizes, int n_in,
                              void* d_out, int out_size, void* d_ws, size_t ws_size,
                              hipStream_t stream) {
  const float* x    = (const float*)d_in[0];
  const float* geom = (const float*)d_in[1];
  const int*   mask = (const int*)d_in[2];
  const float* Wq   = (const float*)d_in[3];
  const float* bq   = (const float*)d_in[4];
  const float* Wk   = (const float*)d_in[5];
  const float* bk   = (const float*)d_in[6];
  const float* Wv   = (const float*)d_in[7];
  const float* bv   = (const float*)d_in[8];
  const float* Wo   = (const float*)d_in[9];
  const float* bo   = (const float*)d_in[10];
  const float* Wg   = (const float*)d_in[11];
  const float* bg   = (const float*)d_in[12];
  float* out = (float*)d_out;

  const size_t NEL = (size_t)BB * SS * DD;  // 4,194,304
  char* p = (char*)d_ws;
  _Float16* xh   = (_Float16*)p;            p += NEL * 2;
  _Float16* Wt   = (_Float16*)p;            p += NEL * 2;
  _Float16* Qh   = (_Float16*)p;            p += NEL * 2;
  _Float16* Kh   = (_Float16*)p;            p += NEL * 2;
  _Float16* Vh   = (_Float16*)p;            p += NEL * 2;
  _Float16* ctxh = (_Float16*)p;            p += NEL * 2;       // 48 MiB base
  unsigned char* bias8 = (unsigned char*)p;                     // +64 MiB (fp8)
  const size_t need = (size_t)48 * 1024 * 1024 + (size_t)BB * NH * SS * SS;
  const bool prebias = ws_size >= need;

  if (prebias) {
    prep2<true><<<7168, 256, 0, stream>>>(x, xh, Wq, Wk, Wv, Wo, Wt,
                                          geom, mask, Wg, bg, bias8);
    gemmQKV<<<768, 256, 0, stream>>>(xh, Wt, bq, bk, bv, Qh, Kh, Vh);
    attnP<<<dim3(SS / 64, NH, BB), 256, 0, stream>>>(Qh, Kh, Vh, bias8, ctxh);
  } else {
    prep2<false><<<3072, 256, 0, stream>>>(x, xh, Wq, Wk, Wv, Wo, Wt,
                                           geom, mask, Wg, bg, nullptr);
    gemmQKV<<<768, 256, 0, stream>>>(xh, Wt, bq, bk, bv, Qh, Kh, Vh);
    attnF<<<dim3(NH, SS / 64, BB), 256, 0, stream>>>(Qh, Kh, Vh, geom, mask, Wg, bg, ctxh);
  }

  hgemm1<<<dim3(32, 8), 256, 0, stream>>>(ctxh, Wt + (size_t)3 * DD * DD, bo, out);
}